// Round 1
// baseline (455.040 us; speedup 1.0000x reference)
//
#include <hip/hip_runtime.h>

#define NB 4096
#define NT 512

// fast sigmoid/tanh via native v_exp_f32 + v_rcp_f32 (safe at +-inf: no NaN)
__device__ __forceinline__ float fsig(float x) {
    return __builtin_amdgcn_rcpf(1.0f + __expf(-x));
}
__device__ __forceinline__ float ftanh(float x) {
    return 2.0f * __builtin_amdgcn_rcpf(1.0f + __expf(-2.0f * x)) - 1.0f;
}

// One 32-lane group per batch element; 2 batches per wave; 64-thread blocks.
// Lane k owns hidden unit k: computes gate rows k, 32+k, 64+k, 96+k with
// W_hh rows held in VGPRs; h is all-gathered through a small LDS buffer.
// Head (fc1 32->16 tanh, fc2 16->1) distributed over lanes 0..15 + shfl reduce.
__global__ __launch_bounds__(64, 2) void lstm_fused_kernel(
    const float* __restrict__ x,
    const float* __restrict__ W_ih,
    const float* __restrict__ W_hh,
    const float* __restrict__ b_ih,
    const float* __restrict__ b_hh,
    const float* __restrict__ W1,
    const float* __restrict__ b1,
    const float* __restrict__ W2,
    const float* __restrict__ b2,
    float* __restrict__ out)
{
    const int tid = threadIdx.x;
    const int grp = tid >> 5;   // 0..1: batch slot within block
    const int k   = tid & 31;   // hidden index owned by this lane
    const int batch = blockIdx.x * 2 + grp;

    // padded to 36 floats (144B) so the two groups' broadcast reads hit
    // different banks; 144 % 16 == 0 keeps float4 alignment
    __shared__ float sh_h[2][36];
    __shared__ float sh_t[2][36];

    // ---- preload weights into registers (loop-invariant) ----
    float Wr[4][32];     // W_hh rows k, 32+k, 64+k, 96+k
    float wih[4][2];
    float bs[4];
    const float4* W4 = (const float4*)W_hh;
#pragma unroll
    for (int g = 0; g < 4; ++g) {
        const int row = g * 32 + k;
#pragma unroll
        for (int q = 0; q < 8; ++q) {
            const float4 w = W4[row * 8 + q];
            Wr[g][4*q+0] = w.x; Wr[g][4*q+1] = w.y;
            Wr[g][4*q+2] = w.z; Wr[g][4*q+3] = w.w;
        }
        wih[g][0] = W_ih[row * 2 + 0];
        wih[g][1] = W_ih[row * 2 + 1];
        bs[g] = b_ih[row] + b_hh[row];
    }

    const int  kd   = (k < 16) ? k : 0;
    float W1r[32];
    const float4* W14 = (const float4*)W1;
#pragma unroll
    for (int q = 0; q < 8; ++q) {
        const float4 w = W14[kd * 8 + q];
        W1r[4*q+0] = w.x; W1r[4*q+1] = w.y;
        W1r[4*q+2] = w.z; W1r[4*q+3] = w.w;
    }
    const float b1r = b1[kd];
    const float w2r = (k < 16) ? W2[k] : 0.0f;
    const float b2v = b2[0];

    // init h in LDS to zero
    sh_h[grp][k] = 0.0f;
    __syncthreads();

    float c = 0.0f;
    const float2* x2 = (const float2*)x;
    const long xbase = (long)batch * NT;
    float* outp = out + (long)batch * NT;
    float2 xv = x2[xbase];   // x at t=0, prefetched

    const float4* hp = (const float4*)(&sh_h[grp][0]);
    const float4* tp = (const float4*)(&sh_t[grp][0]);

    for (int t = 0; t < NT; ++t) {
        // prefetch next x (consumed next iteration -> latency hidden)
        const int tn = (t + 1 < NT) ? (t + 1) : t;
        const float2 xnext = x2[xbase + tn];

        // ---- gates: 4 rows x 32 FMAs, h broadcast from LDS ----
        float a0 = bs[0], a1 = bs[1], a2 = bs[2], a3 = bs[3];
#pragma unroll
        for (int q = 0; q < 8; ++q) {
            const float4 hv = hp[q];
            a0 = fmaf(Wr[0][4*q+0], hv.x, a0);
            a1 = fmaf(Wr[1][4*q+0], hv.x, a1);
            a2 = fmaf(Wr[2][4*q+0], hv.x, a2);
            a3 = fmaf(Wr[3][4*q+0], hv.x, a3);
            a0 = fmaf(Wr[0][4*q+1], hv.y, a0);
            a1 = fmaf(Wr[1][4*q+1], hv.y, a1);
            a2 = fmaf(Wr[2][4*q+1], hv.y, a2);
            a3 = fmaf(Wr[3][4*q+1], hv.y, a3);
            a0 = fmaf(Wr[0][4*q+2], hv.z, a0);
            a1 = fmaf(Wr[1][4*q+2], hv.z, a1);
            a2 = fmaf(Wr[2][4*q+2], hv.z, a2);
            a3 = fmaf(Wr[3][4*q+2], hv.z, a3);
            a0 = fmaf(Wr[0][4*q+3], hv.w, a0);
            a1 = fmaf(Wr[1][4*q+3], hv.w, a1);
            a2 = fmaf(Wr[2][4*q+3], hv.w, a2);
            a3 = fmaf(Wr[3][4*q+3], hv.w, a3);
        }
        a0 = fmaf(xv.x, wih[0][0], fmaf(xv.y, wih[0][1], a0));
        a1 = fmaf(xv.x, wih[1][0], fmaf(xv.y, wih[1][1], a1));
        a2 = fmaf(xv.x, wih[2][0], fmaf(xv.y, wih[2][1], a2));
        a3 = fmaf(xv.x, wih[3][0], fmaf(xv.y, wih[3][1], a3));

        const float ig = fsig(a0);
        const float fg = fsig(a1);
        const float gg = ftanh(a2);
        const float og = fsig(a3);
        c = fmaf(fg, c, ig * gg);
        const float hk  = og * ftanh(c);
        const float thk = ftanh(hk);   // lstm_out = tanh(h)

        __syncthreads();               // all gate reads of old h done
        sh_h[grp][k] = hk;
        sh_t[grp][k] = thk;
        __syncthreads();               // new h/th visible

        // ---- head: fc1 (lanes 0..15) + tanh + fc2 reduce ----
        float f1 = b1r;
#pragma unroll
        for (int q = 0; q < 8; ++q) {
            const float4 tv = tp[q];
            f1 = fmaf(W1r[4*q+0], tv.x, f1);
            f1 = fmaf(W1r[4*q+1], tv.y, f1);
            f1 = fmaf(W1r[4*q+2], tv.z, f1);
            f1 = fmaf(W1r[4*q+3], tv.w, f1);
        }
        float p = ftanh(f1) * w2r;     // w2r==0 for lanes 16..31
        p += __shfl_xor(p, 8);
        p += __shfl_xor(p, 4);
        p += __shfl_xor(p, 2);
        p += __shfl_xor(p, 1);
        if (k == 0) outp[t] = p + b2v;

        xv = xnext;
    }
}

extern "C" void kernel_launch(void* const* d_in, const int* in_sizes, int n_in,
                              void* d_out, int out_size, void* d_ws, size_t ws_size,
                              hipStream_t stream) {
    const float* x    = (const float*)d_in[0];
    const float* W_ih = (const float*)d_in[1];
    const float* W_hh = (const float*)d_in[2];
    const float* b_ih = (const float*)d_in[3];
    const float* b_hh = (const float*)d_in[4];
    const float* W1   = (const float*)d_in[5];
    const float* b1   = (const float*)d_in[6];
    const float* W2   = (const float*)d_in[7];
    const float* b2   = (const float*)d_in[8];
    float* out = (float*)d_out;

    dim3 grid(NB / 2);
    dim3 block(64);
    lstm_fused_kernel<<<grid, block, 0, stream>>>(x, W_ih, W_hh, b_ih, b_hh,
                                                  W1, b1, W2, b2, out);
}